// Round 1
// baseline (114.115 us; speedup 1.0000x reference)
//
#include <hip/hip_runtime.h>
#include <math.h>

#define IMGS 48
#define IMG_ELEMS (512*512)          // 262144 floats per image
#define BLOCKS_A_PER_IMG 64          // 64 blocks * 256 thr * 16 floats = 262144
#define BLOCKS_C_PER_IMG 256         // 256 blocks * 256 thr * 4 floats = 262144

// ---------------- Kernel A: per-block min/max partials ----------------
__global__ __launch_bounds__(256) void minmax_kernel(const float* __restrict__ x,
                                                     float* __restrict__ pmin,
                                                     float* __restrict__ pmax) {
    int blk = blockIdx.x;            // 0..3071
    int img = blk >> 6;              // /64
    int b   = blk & 63;
    const float4* xin = (const float4*)x + (size_t)img * (IMG_ELEMS / 4) + (size_t)b * 1024;
    int t = threadIdx.x;

    float mn = INFINITY, mx = -INFINITY;
#pragma unroll
    for (int k = 0; k < 4; ++k) {
        float4 d = xin[k * 256 + t];
        mn = fminf(mn, fminf(fminf(d.x, d.y), fminf(d.z, d.w)));
        mx = fmaxf(mx, fmaxf(fmaxf(d.x, d.y), fmaxf(d.z, d.w)));
    }
#pragma unroll
    for (int off = 32; off >= 1; off >>= 1) {
        mn = fminf(mn, __shfl_xor(mn, off));
        mx = fmaxf(mx, __shfl_xor(mx, off));
    }
    __shared__ float smn[4], smx[4];
    int wave = t >> 6;
    if ((t & 63) == 0) { smn[wave] = mn; smx[wave] = mx; }
    __syncthreads();
    if (t == 0) {
        mn = fminf(fminf(smn[0], smn[1]), fminf(smn[2], smn[3]));
        mx = fmaxf(fmaxf(smx[0], smx[1]), fmaxf(smx[2], smx[3]));
        pmin[blk] = mn;
        pmax[blk] = mx;
    }
}

// ------- Kernel B: final reduce + sorted boundaries + gap-value table -------
// One block (64 thr, 1 wave) per image.
__global__ __launch_bounds__(64) void bounds_kernel(const float* __restrict__ pmin,
                                                    const float* __restrict__ pmax,
                                                    const float* __restrict__ rp,
                                                    float* __restrict__ wsb,   // [img][16]: sorted boundaries SB[1..15] in slots 0..14
                                                    float* __restrict__ wv) {  // [img][16]: value per sorted gap
    int img  = blockIdx.x;
    int lane = threadIdx.x;

    float mn = pmin[img * 64 + lane];
    float mx = pmax[img * 64 + lane];
#pragma unroll
    for (int off = 32; off >= 1; off >>= 1) {
        mn = fminf(mn, __shfl_xor(mn, off));
        mx = fmaxf(mx, __shfl_xor(mx, off));
    }

    __shared__ float sb[17];   // boundaries, sorted in-place
    __shared__ float L[16], R[16];  // original-order region bounds
    float maxeps = mx + 1e-6f;
    if (lane < 15) {
        // split = rp*(mx-mn)+mn, NO fma contraction (must match XLA mul-then-add)
        float s = __fadd_rn(__fmul_rn(rp[img * 15 + lane], __fsub_rn(mx, mn)), mn);
        sb[1 + lane] = s;
        L[1 + lane]  = s;
        R[lane]      = s;
    }
    if (lane == 0) {
        sb[0] = mn; sb[16] = maxeps;
        L[0]  = mn; R[15]  = maxeps;
    }
    __syncthreads();
    if (lane == 0) {          // insertion-sort 17 values (trivial)
        for (int i = 1; i < 17; ++i) {
            float key = sb[i];
            int j = i - 1;
            while (j >= 0 && sb[j] > key) { sb[j + 1] = sb[j]; --j; }
            sb[j + 1] = key;
        }
    }
    __syncthreads();
    if (lane < 16) {
        // Gap g = lane covers [sb[g], sb[g+1]); region membership is constant
        // inside a gap, so test at sb[g]. First matching region wins (argmax
        // semantics); no match -> L[0] (= min).
        float t = sb[lane];
        float v = L[0];
        bool found = false;
#pragma unroll
        for (int r = 0; r < 16; ++r) {
            bool c = (t >= L[r]) && (t < R[r]);
            if (c && !found) { v = L[r]; found = true; }
        }
        wv[img * 16 + lane] = v;
        if (lane >= 1) wsb[img * 16 + (lane - 1)] = sb[lane];  // SB[1..15]
    }
}

// ---------------- Kernel C: quantize via sorted select ladder ----------------
__global__ __launch_bounds__(256) void quant_kernel(const float* __restrict__ x,
                                                    const float* __restrict__ wsb,
                                                    const float* __restrict__ wv,
                                                    float* __restrict__ out) {
    int blk = blockIdx.x;
    int img = __builtin_amdgcn_readfirstlane(blk >> 8);   // 256 blocks/image, wave-uniform
    const float* SBp = wsb + img * 16;
    const float* Vp  = wv  + img * 16;

    float sb[15], vv[16];
#pragma unroll
    for (int k = 0; k < 15; ++k) sb[k] = SBp[k];
#pragma unroll
    for (int k = 0; k < 16; ++k) vv[k] = Vp[k];

    size_t f4 = (size_t)blk * 256 + threadIdx.x;
    float4 d = ((const float4*)x)[f4];

    float ox = vv[0], oy = vv[0], oz = vv[0], ow = vv[0];
#pragma unroll
    for (int k = 1; k < 16; ++k) {
        ox = (d.x >= sb[k - 1]) ? vv[k] : ox;
        oy = (d.y >= sb[k - 1]) ? vv[k] : oy;
        oz = (d.z >= sb[k - 1]) ? vv[k] : oz;
        ow = (d.w >= sb[k - 1]) ? vv[k] : ow;
    }
    float4 o = make_float4(ox, oy, oz, ow);
    ((float4*)out)[f4] = o;
}

extern "C" void kernel_launch(void* const* d_in, const int* in_sizes, int n_in,
                              void* d_out, int out_size, void* d_ws, size_t ws_size,
                              hipStream_t stream) {
    const float* x  = (const float*)d_in[0];
    const float* rp = (const float*)d_in[1];
    float* out = (float*)d_out;
    float* ws  = (float*)d_ws;

    float* pmin = ws;              // 48*64 = 3072 floats
    float* pmax = ws + 3072;       // 3072 floats
    float* wsb  = ws + 6144;       // 48*16 = 768 floats
    float* wv   = ws + 6912;       // 768 floats  (total 30 KB < ws_size)

    minmax_kernel<<<IMGS * BLOCKS_A_PER_IMG, 256, 0, stream>>>(x, pmin, pmax);
    bounds_kernel<<<IMGS, 64, 0, stream>>>(pmin, pmax, rp, wsb, wv);
    quant_kernel<<<IMGS * BLOCKS_C_PER_IMG, 256, 0, stream>>>(x, wsb, wv, out);
}

// Round 3
// 110.908 us; speedup vs baseline: 1.0289x; 1.0289x over previous
//
#include <hip/hip_runtime.h>
#include <math.h>

#define IMGS 48
#define IMG_ELEMS (512*512)          // 262144 floats per image
#define BLOCKS_A_PER_IMG 64          // 64 blocks * 256 thr * 16 floats = 262144
#define BLOCKS_C_PER_IMG 64          // 64 blocks * 256 thr * 16 floats = 262144

// ---------------- Kernel A: per-block min/max partials ----------------
__global__ __launch_bounds__(256) void minmax_kernel(const float* __restrict__ x,
                                                     float* __restrict__ pmin,
                                                     float* __restrict__ pmax) {
    int blk = blockIdx.x;            // 0..3071
    int img = blk >> 6;              // /64
    int b   = blk & 63;
    const float4* xin = (const float4*)x + (size_t)img * (IMG_ELEMS / 4) + (size_t)b * 1024;
    int t = threadIdx.x;

    float mn = INFINITY, mx = -INFINITY;
#pragma unroll
    for (int k = 0; k < 4; ++k) {
        float4 d = xin[k * 256 + t];
        mn = fminf(mn, fminf(fminf(d.x, d.y), fminf(d.z, d.w)));
        mx = fmaxf(mx, fmaxf(fmaxf(d.x, d.y), fmaxf(d.z, d.w)));
    }
#pragma unroll
    for (int off = 32; off >= 1; off >>= 1) {
        mn = fminf(mn, __shfl_xor(mn, off));
        mx = fmaxf(mx, __shfl_xor(mx, off));
    }
    __shared__ float smn[4], smx[4];
    int wave = t >> 6;
    if ((t & 63) == 0) { smn[wave] = mn; smx[wave] = mx; }
    __syncthreads();
    if (t == 0) {
        pmin[blk] = fminf(fminf(smn[0], smn[1]), fminf(smn[2], smn[3]));
        pmax[blk] = fmaxf(fmaxf(smx[0], smx[1]), fmaxf(smx[2], smx[3]));
    }
}

// ------ Kernel C: fused bounds (wave 0, hidden under x loads) + quantize ------
// Per block: issue this thread's 4 float4 x-loads first; while they are in
// flight, wave 0 redundantly computes the image's min/max (64 partials from
// L2), the 17 sorted boundaries (wave-parallel rank sort) and the 16 gap
// values (first-matching-region rule = argmax semantics), publishing the
// 31-float table via LDS. Then the select ladder maps x -> quantized value.
__global__ __launch_bounds__(256) void quant_fused(const float* __restrict__ x,
                                                   const float* __restrict__ pmin,
                                                   const float* __restrict__ pmax,
                                                   const float* __restrict__ rp,
                                                   float* __restrict__ out) {
    int blk  = blockIdx.x;
    int img  = blk >> 6;                 // 64 blocks/image
    int b    = blk & 63;
    int t    = threadIdx.x;
    int lane = t & 63;
    int wave = t >> 6;

    __shared__ float sorted[17];
    __shared__ float s_sb[15], s_vv[16];

    // ---- issue global loads of x early (independent of the preamble) ----
    size_t base = (size_t)img * (IMG_ELEMS / 4) + (size_t)b * 1024 + t;
    const float4* xin = (const float4*)x + base;
    float4 d0 = xin[0];
    float4 d1 = xin[256];
    float4 d2 = xin[512];
    float4 d3 = xin[768];

    if (wave == 0) {
        // final min/max reduce over this image's 64 partials
        float mn = pmin[img * 64 + lane];
        float mx = pmax[img * 64 + lane];
#pragma unroll
        for (int off = 32; off >= 1; off >>= 1) {
            mn = fminf(mn, __shfl_xor(mn, off));
            mx = fmaxf(mx, __shfl_xor(mx, off));
        }
        float maxeps = __fadd_rn(mx, 1e-6f);

        // boundary per lane: lane0=mn, lanes1..15=split[lane-1], lane16=mx+1e-6
        float u = (lane >= 1 && lane <= 15) ? rp[img * 15 + (lane - 1)] : 0.0f;
        // split = u*(mx-mn)+mn, explicit mul-then-add (match XLA, no FMA)
        float split = __fadd_rn(__fmul_rn(u, __fsub_rn(mx, mn)), mn);
        float bval  = (lane == 0) ? mn : (lane == 16 ? maxeps : split);

        // stable rank among lanes 0..16 (unique ranks; ties by lane index)
        int rank = 0;
#pragma unroll
        for (int i = 0; i < 17; ++i) {
            float vi = __shfl(bval, i);
            rank += (vi < bval) || (vi == bval && i < lane);
        }
        if (lane < 17) sorted[rank] = bval;   // intra-wave: waitcnt, no barrier

        // gap g covers [sorted[g], sorted[g+1]); membership constant inside a
        // gap -> evaluate first-matching original region at tg = sorted[g].
        float tg = sorted[lane & 15];
        float v  = __shfl(bval, 0);           // = mn (no-match default)
        bool found = false;
#pragma unroll
        for (int r = 0; r < 16; ++r) {
            float Lr = __shfl(bval, r);       // L[0]=mn, L[r]=split[r-1]
            float Rr = __shfl(bval, r + 1);   // R[r]=L[r+1], R[15]=maxeps
            bool c = (tg >= Lr) && (tg < Rr);
            v = (c && !found) ? Lr : v;
            found = found || c;
        }
        if (lane < 16)  s_vv[lane] = v;
        if (lane < 15)  s_sb[lane] = sorted[lane + 1];   // thresholds SB[1..15]
    }
    __syncthreads();

    float sb[15], vv[16];
#pragma unroll
    for (int k = 0; k < 15; ++k) sb[k] = s_sb[k];
#pragma unroll
    for (int k = 0; k < 16; ++k) vv[k] = s_vv[k];

    float4* oput = (float4*)out + base;
    float4 din[4] = {d0, d1, d2, d3};
#pragma unroll
    for (int k = 0; k < 4; ++k) {
        float4 d = din[k];
        float ox = vv[0], oy = vv[0], oz = vv[0], ow = vv[0];
#pragma unroll
        for (int j = 1; j < 16; ++j) {
            ox = (d.x >= sb[j - 1]) ? vv[j] : ox;
            oy = (d.y >= sb[j - 1]) ? vv[j] : oy;
            oz = (d.z >= sb[j - 1]) ? vv[j] : oz;
            ow = (d.w >= sb[j - 1]) ? vv[j] : ow;
        }
        oput[k * 256] = make_float4(ox, oy, oz, ow);
    }
}

extern "C" void kernel_launch(void* const* d_in, const int* in_sizes, int n_in,
                              void* d_out, int out_size, void* d_ws, size_t ws_size,
                              hipStream_t stream) {
    const float* x  = (const float*)d_in[0];
    const float* rp = (const float*)d_in[1];
    float* out = (float*)d_out;
    float* ws  = (float*)d_ws;

    float* pmin = ws;              // 48*64 = 3072 floats
    float* pmax = ws + 3072;       // 3072 floats

    minmax_kernel<<<IMGS * BLOCKS_A_PER_IMG, 256, 0, stream>>>(x, pmin, pmax);
    quant_fused<<<IMGS * BLOCKS_C_PER_IMG, 256, 0, stream>>>(x, pmin, pmax, rp, out);
}